// Round 10
// baseline (4448.430 us; speedup 1.0000x reference)
//
#include <hip/hip_runtime.h>
#include <cstdint>
#include <cstddef>

// ============================================================================
// ViT forward, MI355X. Round 9: 256x256 GEMM tile (131 FLOP/staged-byte vs 87),
// ring-3 prefetch (full K-step cover), 8 waves 2Mx4N, setprio around MFMA.
// QKV fused along N (Q|K|V -> N=2304; wbuf already stacked). MLP2 split-K3
// with fp32 partials P1/P2 folded into next LN / head (R7 machinery).
// Wo/embed keep the 4-wave path.
// Workspace (155,910,144 B):
//   x    f32  @ 0
//   attn bf16 @ 25559040   } aliases P1 (disjoint lifetimes)
//   P1   f32  @ 25559040 (ends 51118080)
//   qkv  bf16 [8320][2304] @ 38338560 (ends 76677120; overlaps P1-tail/P2 --
//        qkv live [QKV-write .. attn-read], P1/P2 live [MLP2 .. next ln1) ✓)
//   P2   f32  @ 51118080 (ends 76677120)
//   h    bf16 @ 76677120    mid bf16 @ 89456640 [patches alias]
//   wbuf bf16 @ 140574720   lwt bf16 @ 154730496
// ============================================================================

typedef __bf16 bf16x8 __attribute__((ext_vector_type(8)));
typedef float  f32x4  __attribute__((ext_vector_type(4)));

#define DEVINL __device__ __forceinline__

DEVINL uint16_t f2bf(float f){
  union U{float f; uint32_t i;} v; v.f=f; uint32_t u=v.i;
  return (uint16_t)((u + 0x7fffu + ((u>>16)&1u)) >> 16);   // RNE
}

DEVINL void gl_lds16(const void* g, void* l){
  __builtin_amdgcn_global_load_lds((const __attribute__((address_space(1))) void*)g,
                                   (__attribute__((address_space(3))) void*)l, 16, 0, 0);
}

// ---------------- patchify
__global__ __launch_bounds__(256) void patchify_k(const float* __restrict__ img,
                                                  uint16_t* __restrict__ out){
  int i = blockIdx.x*256 + threadIdx.x;
  int m  = i / 768, kk = i - m*768;
  int b  = m >> 6,  t  = m & 63;
  int py = t >> 3,  px = t & 7;
  int r  = kk / 48, rem = kk - r*48;
  size_t src = ((size_t)(b*128 + py*16 + r)*128 + px*16)*3 + rem;
  out[i] = f2bf(img[src]);
}

// ---------------- 32x32 transpose + f32->bf16
DEVINL void tile_transpose(const float* __restrict__ src, uint16_t* __restrict__ dst,
                           int R, int C, int ti, int tj, int tid){
  __shared__ uint16_t tile[32][33];
  int tx = tid & 31, ty = tid >> 5;
  int r0 = ti*32, c0 = tj*32;
  #pragma unroll
  for (int i=0;i<4;++i)
    tile[ty+i*8][tx] = f2bf(src[(size_t)(r0+ty+i*8)*C + c0 + tx]);
  __syncthreads();
  #pragma unroll
  for (int i=0;i<4;++i)
    dst[(size_t)(c0+ty+i*8)*R + r0 + tx] = tile[tx][ty+i*8];
}

__global__ __launch_bounds__(256) void transpose_cvt_k(const float* __restrict__ src,
                                                       uint16_t* __restrict__ dst, int R, int C){
  tile_transpose(src, dst, R, C, blockIdx.y, blockIdx.x, threadIdx.x);
}

__global__ __launch_bounds__(256) void prep_layer_k(
    const float* __restrict__ Wq, const float* __restrict__ Wk,
    const float* __restrict__ Wv, const float* __restrict__ Wo,
    const float* __restrict__ W1, const float* __restrict__ W2,
    uint16_t* __restrict__ wbuf){
  int idx = blockIdx.x;
  const float* src; uint16_t* dst; int R, C, ti, tj;
  if (idx < 2304){
    int m = idx / 576, t = idx - m*576; ti = t/24; tj = t - ti*24; R=768; C=768;
    src = (m==0)?Wq:(m==1)?Wk:(m==2)?Wv:Wo;
    dst = wbuf + (size_t)m*589824;
  } else if (idx < 4608){
    int t = idx - 2304; ti = t/96; tj = t - ti*96; R=768; C=3072;
    src = W1; dst = wbuf + 2359296;
  } else {
    int t = idx - 4608; ti = t/24; tj = t - ti*24; R=3072; C=768;
    src = W2; dst = wbuf + 4718592;
  }
  tile_transpose(src, dst, R, C, ti, tj, threadIdx.x);
}

__global__ __launch_bounds__(256) void cls_init_k(const float* __restrict__ ct,
                                                  const float* __restrict__ pos,
                                                  float* __restrict__ X){
  int b = blockIdx.x, tid = threadIdx.x;
  for (int e = tid; e < 768; e += 256)
    X[(size_t)b*65*768 + e] = ct[e] + pos[e];
}

// ---------------- LayerNorm; SUMP: x += P1 + P2 first (split-K3 reduce fused)
template<int SUMP>
__global__ __launch_bounds__(256) void ln_k(const float* __restrict__ Xin,
                                            float* __restrict__ Xout,
                                            const float* __restrict__ P1,
                                            const float* __restrict__ P2,
                                            uint16_t* __restrict__ H,
                                            const float* __restrict__ g,
                                            const float* __restrict__ b){
  int row = blockIdx.x, tid = threadIdx.x;
  const size_t ro = (size_t)row*768;
  const float* xr = Xin + ro;
  float v0, v1, v2;
  if constexpr (SUMP){
    const float* p1 = P1 + ro; const float* p2 = P2 + ro;
    v0 = xr[tid]     + p1[tid]     + p2[tid];
    v1 = xr[tid+256] + p1[tid+256] + p2[tid+256];
    v2 = xr[tid+512] + p1[tid+512] + p2[tid+512];
    float* xo = Xout + ro;
    xo[tid] = v0; xo[tid+256] = v1; xo[tid+512] = v2;
  } else {
    v0 = xr[tid]; v1 = xr[tid+256]; v2 = xr[tid+512];
  }
  int wid = tid>>6, lane = tid&63;
  __shared__ float part[4];
  __shared__ float bc[2];
  float s = v0+v1+v2;
  #pragma unroll
  for (int o=32;o;o>>=1) s += __shfl_down(s,o);
  if (lane==0) part[wid] = s;
  __syncthreads();
  if (tid==0) bc[0] = (part[0]+part[1]+part[2]+part[3]) * (1.f/768.f);
  __syncthreads();
  float mu = bc[0];
  float d0=v0-mu, d1=v1-mu, d2=v2-mu;
  float q = d0*d0 + d1*d1 + d2*d2;
  #pragma unroll
  for (int o=32;o;o>>=1) q += __shfl_down(q,o);
  __syncthreads();
  if (lane==0) part[wid] = q;
  __syncthreads();
  if (tid==0) bc[1] = rsqrtf((part[0]+part[1]+part[2]+part[3])*(1.f/768.f) + 1e-5f);
  __syncthreads();
  float rs = bc[1];
  uint16_t* hr = H + ro;
  hr[tid]     = f2bf(d0*rs*g[tid]     + b[tid]);
  hr[tid+256] = f2bf(d1*rs*g[tid+256] + b[tid+256]);
  hr[tid+512] = f2bf(d2*rs*g[tid+512] + b[tid+512]);
}

enum { EP_BF16=0, EP_RES=1, EP_RELU=2, EP_EMB=3 };

// ---------------- 4-wave GEMM (BM=128, BN 64/128) — embed + Wo only
template<int MODE, int BN>
__global__ __launch_bounds__(256) void gemm_bt_k(
    const uint16_t* __restrict__ A, const uint16_t* __restrict__ Bt,
    int M, int N, int K, int strideB, long long strideO,
    const float* __restrict__ bias, float* __restrict__ X,
    uint16_t* __restrict__ Obf, const float* __restrict__ pos)
{
  constexpr int WN = BN/2;
  constexpr int NF = WN/16;
  constexpr int BLOADS = BN/64;
  __shared__ __align__(16) uint16_t sA[3][128*32];
  __shared__ __align__(16) uint16_t sB[3][BN*32];
  const int tid = threadIdx.x;
  const int wid = tid>>6, lane = tid&63;
  const int nx = gridDim.x;
  const int nwg = nx*gridDim.y;
  int idx = blockIdx.y*nx + blockIdx.x;
  int q8 = nwg>>3, r8 = nwg&7, xcd = idx&7, off = idx>>3;
  int swz = (xcd<r8 ? xcd*(q8+1) : r8*(q8+1) + (xcd-r8)*q8) + off;
  const int bn = (swz % nx)*BN, bm = (swz / nx)*128;
  const int z = blockIdx.z;
  const uint16_t* Bz = Bt + (size_t)z*strideB;
  const int wr = wid>>1, wc = wid&1;
  const int frow = lane&15, g = lane>>4;
  int srA[2], scA[2];
  #pragma unroll
  for (int rr=0; rr<2; ++rr){
    int G = rr*256 + tid;
    srA[rr] = G>>2; scA[rr] = ((G&3) - (G>>3)) & 3;
  }
  int srB[BLOADS], scB[BLOADS];
  #pragma unroll
  for (int rr=0; rr<BLOADS; ++rr){
    int G = rr*256 + tid;
    srB[rr] = G>>2; scB[rr] = ((G&3) - (G>>3)) & 3;
  }
  const int rsw = (frow>>1)&3;
  f32x4 acc[4][NF] = {};
  const int nt = K>>5;

  auto stage = [&](char* dA, char* dB, int k0){
    #pragma unroll
    for (int rr=0; rr<2; ++rr)
      gl_lds16(A + (size_t)(bm+srA[rr])*K + k0 + scA[rr]*8, dA + (rr*256 + wid*64)*16);
    #pragma unroll
    for (int rr=0; rr<BLOADS; ++rr)
      gl_lds16(Bz + (size_t)(bn+srB[rr])*K + k0 + scB[rr]*8, dB + (rr*256 + wid*64)*16);
  };

  char *cA=(char*)sA[0], *nA=(char*)sA[1], *fA=(char*)sA[2];
  char *cB=(char*)sB[0], *nB=(char*)sB[1], *fB=(char*)sB[2];
  stage(cA, cB, 0);
  stage(nA, nB, 32);

  for (int t = 0; t < nt; ++t){
    if (t+2 < nt){
      stage(fA, fB, (t+2)<<5);
      if constexpr (BLOADS==1) asm volatile("s_waitcnt vmcnt(6)" ::: "memory");
      else                     asm volatile("s_waitcnt vmcnt(8)" ::: "memory");
    } else if (t+1 < nt){
      if constexpr (BLOADS==1) asm volatile("s_waitcnt vmcnt(3)" ::: "memory");
      else                     asm volatile("s_waitcnt vmcnt(4)" ::: "memory");
    } else {
      asm volatile("s_waitcnt vmcnt(0)" ::: "memory");
    }
    __builtin_amdgcn_s_barrier();
    bf16x8 a[4], b[NF];
    #pragma unroll
    for (int m=0;m<4;++m)
      a[m] = *(const bf16x8*)(cA + (wr*64+m*16+frow)*64 + (((g+rsw)&3)<<4));
    #pragma unroll
    for (int n=0;n<NF;++n)
      b[n] = *(const bf16x8*)(cB + (wc*WN+n*16+frow)*64 + (((g+rsw)&3)<<4));
    #pragma unroll
    for (int m=0;m<4;++m)
      #pragma unroll
      for (int n=0;n<NF;++n)
        acc[m][n] = __builtin_amdgcn_mfma_f32_16x16x32_bf16(a[m], b[n], acc[m][n], 0,0,0);
    __builtin_amdgcn_s_barrier();
    char* t1=cA; cA=nA; nA=fA; fA=t1;
    char* t2=cB; cB=nB; nB=fB; fB=t2;
  }

  uint16_t* Oz = Obf + (size_t)z*(size_t)strideO;
  #pragma unroll
  for (int m=0;m<4;++m){
    int gr0 = bm + wr*64 + m*16 + (lane>>4)*4;
    #pragma unroll
    for (int n=0;n<NF;++n){
      int gc = bn + wc*WN + n*16 + (lane&15);
      #pragma unroll
      for (int r=0;r<4;++r){
        int grow = gr0 + r;
        float vsum = acc[m][n][r];
        if constexpr (MODE==EP_BF16){
          Oz[(size_t)grow*N + gc] = f2bf(vsum);
        } else if constexpr (MODE==EP_RES){
          X[(size_t)grow*N + gc] += vsum + bias[gc];
        } else if constexpr (MODE==EP_RELU){
          float u = vsum + bias[gc];
          Oz[(size_t)grow*N + gc] = f2bf(u > 0.f ? u : 0.f);
        } else {
          int t2i = grow & 63, bb = grow >> 6;
          X[((size_t)bb*65 + 1 + t2i)*768 + gc] = vsum + pos[(size_t)(t2i+1)*768 + gc];
        }
      }
    }
  }
}

// ---------------- 8-wave 256x256 GEMM: QKV(fused N) / MLP1 / MLP2(SK3)
// Waves 2M x 4N (wave tile 128x64, 8x4 frags). BK=32, ring-3 prefetch
// (vmcnt(8) steady: 2 batches x 4 loads in flight -> full K-step cover).
// 131 FLOP/staged-byte. setprio(1) around the 32-MFMA cluster (T5).
// SK==3 (EP_RES): z0 X+=bias RMW, z1->P1, z2->P2 (folded into next ln/head).
// M-tail store-guarded (OOB A-reads stay inside ws).
template<int MODE, int SK>
__global__ __launch_bounds__(512) void gemm256_k(
    const uint16_t* __restrict__ A, const uint16_t* __restrict__ Bt,
    int M, int N, int K,
    const float* __restrict__ bias, float* __restrict__ X,
    uint16_t* __restrict__ Obf, float* __restrict__ P1, float* __restrict__ P2)
{
  __shared__ __align__(16) uint16_t sA[3][256*32];
  __shared__ __align__(16) uint16_t sB[3][256*32];
  const int tid = threadIdx.x;
  const int wid = tid>>6, lane = tid&63;
  const int nx = gridDim.x;
  const int nwg = nx*gridDim.y;
  int idx = blockIdx.y*nx + blockIdx.x;
  int q8 = nwg>>3, r8 = nwg&7, xcd = idx&7, off = idx>>3;
  int swz = (xcd<r8 ? xcd*(q8+1) : r8*(q8+1) + (xcd-r8)*q8) + off;
  const int bn = (swz % nx)*256, bm = (swz / nx)*256;
  const int z = blockIdx.z;
  const int kbase = (SK==1) ? 0 : z*(K/SK);
  const int KS = (SK==1) ? K : K/SK;
  const int wr = wid>>2, wc = wid&3;               // 2M x 4N
  const int frow = lane&15, g = lane>>4;
  int sr[2], sc[2];
  #pragma unroll
  for (int rr=0; rr<2; ++rr){
    int G = rr*512 + tid;                          // 1024 granules = 256 rows x 4
    sr[rr] = G>>2; sc[rr] = ((G&3) - (G>>3)) & 3;
  }
  const int rsw = (frow>>1)&3;
  f32x4 acc[8][4] = {};
  const int nt = KS>>5;

  auto stage = [&](int bsel, int k0){
    char* dA = (char*)sA[bsel]; char* dB = (char*)sB[bsel];
    #pragma unroll
    for (int rr=0; rr<2; ++rr){
      gl_lds16(A  + (size_t)(bm+sr[rr])*K + kbase + k0 + sc[rr]*8,
               dA + (rr*512 + wid*64)*16);
      gl_lds16(Bt + (size_t)(bn+sr[rr])*K + kbase + k0 + sc[rr]*8,
               dB + (rr*512 + wid*64)*16);
    }
  };

  stage(0, 0);
  stage(1, 32);
  int cur = 0;
  for (int t = 0; t < nt; ++t){
    if (t+2 < nt){
      stage((cur+2)%3, (t+2)<<5);
      asm volatile("s_waitcnt vmcnt(8)" ::: "memory");
    } else if (t+1 < nt){
      asm volatile("s_waitcnt vmcnt(4)" ::: "memory");
    } else {
      asm volatile("s_waitcnt vmcnt(0)" ::: "memory");
    }
    __builtin_amdgcn_s_barrier();                  // batch t landed
    const char* sAc = (const char*)sA[cur];
    const char* sBc = (const char*)sB[cur];
    bf16x8 a[8], b[4];
    #pragma unroll
    for (int m=0;m<8;++m)
      a[m] = *(const bf16x8*)(sAc + (wr*128+m*16+frow)*64 + (((g+rsw)&3)<<4));
    #pragma unroll
    for (int n=0;n<4;++n)
      b[n] = *(const bf16x8*)(sBc + (wc*64+n*16+frow)*64 + (((g+rsw)&3)<<4));
    __builtin_amdgcn_s_setprio(1);
    #pragma unroll
    for (int m=0;m<8;++m)
      #pragma unroll
      for (int n=0;n<4;++n)
        acc[m][n] = __builtin_amdgcn_mfma_f32_16x16x32_bf16(a[m], b[n], acc[m][n], 0,0,0);
    __builtin_amdgcn_s_setprio(0);
    __builtin_amdgcn_s_barrier();                  // done reading cur
    cur = (cur+1)%3;
  }

  #pragma unroll
  for (int m=0;m<8;++m){
    int gr0 = bm + wr*128 + m*16 + (lane>>4)*4;
    #pragma unroll
    for (int n=0;n<4;++n){
      int gc = bn + wc*64 + n*16 + (lane&15);
      #pragma unroll
      for (int r=0;r<4;++r){
        int grow = gr0 + r;
        if (grow < M){
          float vsum = acc[m][n][r];
          if constexpr (MODE==EP_BF16){
            Obf[(size_t)grow*N + gc] = f2bf(vsum);
          } else if constexpr (MODE==EP_RES){
            if (z==0)      X[(size_t)grow*N + gc] += vsum + bias[gc];
            else if (z==1) P1[(size_t)grow*N + gc] = vsum;
            else           P2[(size_t)grow*N + gc] = vsum;
          } else if constexpr (MODE==EP_RELU){
            float u = vsum + bias[gc];
            Obf[(size_t)grow*N + gc] = f2bf(u > 0.f ? u : 0.f);
          }
        }
      }
    }
  }
}

// ---------------- MFMA attention over fused qkv [8320][2304]
__global__ __launch_bounds__(320) void attn_mfma_k(const uint16_t* __restrict__ qkv,
    uint16_t* __restrict__ o)
{
  __shared__ __align__(16) uint16_t P_lds[80][104];
  __shared__ __align__(16) uint16_t Vt[64][104];
  const int bh = blockIdx.x; const int b = bh / 12, hd = bh - b*12;
  const int tid = threadIdx.x;
  const int m = tid>>6;
  const int lane = tid&63;
  const int g = lane>>4, c = lane&15;
  const size_t base  = (size_t)b*65*2304 + (size_t)hd*64;   // Q cols
  const size_t obase = (size_t)b*65*768  + (size_t)hd*64;

  for (int i = tid; i < 80*16; i += 320) P_lds[i>>4][80 + (i&15)] = 0;
  for (int i = tid; i < 64*32; i += 320) Vt[i>>5][64 + (i&31)] = 0;
  __syncthreads();
  for (int j = tid; j < 520; j += 320){
    int key = j >> 3, dc = j & 7;
    union { bf16x8 v8; uint16_t u[8]; } gv;
    gv.v8 = *(const bf16x8*)&qkv[base + 1536 + (size_t)key*2304 + dc*8];
    #pragma unroll
    for (int e = 0; e < 8; ++e) Vt[dc*8 + e][key] = gv.u[e];
  }

  bf16x8 bk[5][2];
  #pragma unroll
  for (int n=0;n<5;++n)
    #pragma unroll
    for (int kk=0;kk<2;++kk)
      bk[n][kk] = *(const bf16x8*)&qkv[base + 768 + (size_t)(n*16 + c)*2304 + kk*32 + g*8];

  bf16x8 aq[2];
  #pragma unroll
  for (int kk=0;kk<2;++kk)
    aq[kk] = *(const bf16x8*)&qkv[base + (size_t)(m*16 + c)*2304 + kk*32 + g*8];
  f32x4 sacc[5] = {};
  #pragma unroll
  for (int kk=0;kk<2;++kk)
    #pragma unroll
    for (int n=0;n<5;++n)
      sacc[n] = __builtin_amdgcn_mfma_f32_16x16x32_bf16(aq[kk], bk[n][kk], sacc[n], 0,0,0);

  const float scale = 0.03608439182435161f;
  #pragma unroll
  for (int r=0;r<4;++r){
    float val[5]; float mx = -3.0e38f;
    #pragma unroll
    for (int n=0;n<5;++n){
      val[n] = (n*16 + c) < 65 ? sacc[n][r]*scale : -3.0e38f;
      mx = fmaxf(mx, val[n]);
    }
    #pragma unroll
    for (int off=1; off<16; off<<=1) mx = fmaxf(mx, __shfl_xor(mx, off));
    float p[5], sum = 0.f;
    #pragma unroll
    for (int n=0;n<5;++n){
      p[n] = (n*16 + c) < 65 ? __expf(val[n]-mx) : 0.f;
      sum += p[n];
    }
    #pragma unroll
    for (int off=1; off<16; off<<=1) sum += __shfl_xor(sum, off);
    float rinv = 1.f / sum;
    int row = m*16 + g*4 + r;
    #pragma unroll
    for (int n=0;n<5;++n) P_lds[row][n*16 + c] = f2bf(p[n]*rinv);
  }
  __syncthreads();

  bf16x8 vb[4][3];
  #pragma unroll
  for (int n=0;n<4;++n)
    #pragma unroll
    for (int kk=0;kk<3;++kk)
      vb[n][kk] = *(const bf16x8*)&Vt[n*16 + c][kk*32 + g*8];
  f32x4 oacc[4] = {};
  #pragma unroll
  for (int kk=0;kk<3;++kk){
    bf16x8 pa = *(const bf16x8*)&P_lds[m*16 + c][kk*32 + g*8];
    #pragma unroll
    for (int n=0;n<4;++n)
      oacc[n] = __builtin_amdgcn_mfma_f32_16x16x32_bf16(pa, vb[n][kk], oacc[n], 0,0,0);
  }
  #pragma unroll
  for (int r=0;r<4;++r){
    int row = m*16 + g*4 + r;
    if (row < 65){
      #pragma unroll
      for (int n=0;n<4;++n)
        o[obase + (size_t)row*768 + n*16 + c] = f2bf(oacc[r==r?r:r, oacc[n][r]*0.f==0.f ? n : n][r]);
    }
  }
}

// ---------------- head: logits = softmax((x+P1+P2)[cls] @ head_w + b)
__global__ __launch_bounds__(256) void head_k(const float* __restrict__ X,
    const float* __restrict__ P1, const float* __restrict__ P2,
    const float* __restrict__ W, const float* __restrict__ bias,
    float* __restrict__ out){
  int b = blockIdx.x, a = threadIdx.x;
  const size_t ro = (size_t)b*65*768;
  const float* xr = X + ro;
  const float* p1 = P1 + ro;
  const float* p2 = P2 + ro;
  float acc = bias[a];
  for (int kk=0; kk<768; ++kk)
    acc += (xr[kk]+p1[kk]+p2[kk])*W[(size_t)kk*256 + a];
  int wid = a>>6, lane = a&63;
  __shared__ float red[4];
  float mx = acc;
  #pragma unroll
  for (int off=32; off; off>>=1) mx = fmaxf(mx, __shfl_xor(mx, off));
  if (lane==0) red[wid]=mx;
  __syncthreads();
  mx = fmaxf(fmaxf(red[0],red[1]), fmaxf(red[2],red[3]));
  float e = __expf(acc-mx);
  float s = e;
  #pragma unroll
  for (int off=32; off; off>>=1) s += __shfl_xor(s, off);
  __syncthreads();
  if (lane==0) red[wid]=s;
  __syncthreads();
  s = red[0]+red[1]+red[2]+red[3];
  out[(size_t)b*256 + a] = e/s;
}

// ============================================================================
extern "C" void kernel_launch(void* const* d_in, const int* in_sizes, int n_in,
                              void* d_out, int out_size, void* d_ws, size_t ws_size,
                              hipStream_t stream)
{
  const float* images = (const float*)d_in[0];
  const float* lin_w  = (const float*)d_in[1];
  const float* cls_tok= (const float*)d_in[2];
  const float* pos    = (const float*)d_in[3];
  const float* Wq = (const float*)d_in[4];
  const float* Wk = (const float*)d_in[5];
  const float* Wv = (const float*)d_in[6];
  const float* Wo = (const float*)d_in[7];
  const float* bo = (const float*)d_in[8];
  const float* ln1g=(const float*)d_in[9];
  const float* ln1b=(const float*)d_in[10];
  const float* ln2g=(const float*)d_in[11];
  const float* ln2b=(const float*)d_in[12];
  const float* W1 = (const float*)d_in[13];
  const float* b1 = (const float*)d_in[14];
  const float* W2 = (const float*)d_in[15];
  const float* b2 = (const float*)d_in[16];
  const float* hw = (const float*)d_in[17];
  const float* hb = (const float*)d_in[18];

  char* ws = (char*)d_ws;
  float*    x    = (float*)   (ws + 0);
  uint16_t* attn = (uint16_t*)(ws + 25559040);     // aliases P1 (disjoint phases)
  float*    P1   = (float*)   (ws + 25559040);
  uint16_t* qkv  = (uint16_t*)(ws + 38338560);     // fused [8320][2304]
  float*    P2   = (float*)   (ws + 51118080);
  uint16_t* h    = (uint16_t*)(ws + 76677120);
  uint16_t* mid  = (uint16_t*)(ws + 89456640);     // patches alias
  uint16_t* wbuf = (uint16_t*)(ws + 140574720);
  uint16_t* lwt  = (uint16_t*)(ws + 154730496);

  // embed
  patchify_k<<<24576,256,0,stream>>>(images, mid);
  transpose_cvt_k<<<dim3(24,24),256,0,stream>>>(lin_w, lwt, 768, 768);
  gemm_bt_k<EP_EMB,64><<<dim3(12,64,1),256,0,stream>>>(mid, lwt, 8192,768,768, 0,0,
                                                   nullptr, x, nullptr, pos);
  cls_init_k<<<128,256,0,stream>>>(cls_tok, pos, x);

  for (int l=0;l<12;++l){
    prep_layer_k<<<6912,256,0,stream>>>(Wq+(size_t)l*589824, Wk+(size_t)l*589824,
                                        Wv+(size_t)l*589824, Wo+(size_t)l*589824,
                                        W1+(size_t)l*2359296, W2+(size_t)l*2359296, wbuf);
    if (l==0)
      ln_k<0><<<8320,256,0,stream>>>(x, nullptr, nullptr, nullptr, h, ln1g, ln1b);
    else
      ln_k<1><<<8320,256,0,stream>>>(x, x, P1, P2, h,
                                     ln1g+(size_t)l*768, ln1b+(size_t)l*768);
    gemm256_k<EP_BF16,1><<<dim3(9,33,1),512,0,stream>>>(h, wbuf, 8320,2304,768,
                                                        nullptr, nullptr, qkv, nullptr, nullptr);
    attn_mfma_k<<<1536,320,0,stream>>>(qkv, attn);
    gemm_bt_k<EP_RES,64><<<dim3(12,65,1),256,0,stream>>>(attn, wbuf+1769472, 8320,768,768,
                                                     0,0, bo+(size_t)l*768, x, nullptr, nullptr);
    ln_k<0><<<8320,256,0,stream>>>(x, nullptr, nullptr, nullptr, h,
                                   ln2g+(size_t)l*768, ln2b+(size_t)l*768);
    gemm256_k<EP_RELU,1><<<dim3(12,33,1),512,0,stream>>>(h, wbuf+2359296, 8320,3072,768,
                                                         b1+(size_t)l*3072, nullptr, mid, nullptr, nullptr);
    gemm256_k<EP_RES,3><<<dim3(3,33,3),512,0,stream>>>(mid, wbuf+4718592, 8320,768,3072,
                                                       b2+(size_t)l*768, x, nullptr, P1, P2);
  }
  head_k<<<128,256,0,stream>>>(x, P1, P2, hw, hb, (float*)d_out);
}

// Round 11
// 3099.724 us; speedup vs baseline: 1.4351x; 1.4351x over previous
//
#include <hip/hip_runtime.h>
#include <cstdint>
#include <cstddef>

// ============================================================================
// ViT forward, MI355X. Round 10: revert R10's 256x256 (1 blk/CU disaster);
// base = R9. Fix the hidden Wo cost (95us @ ~110 TF, fp32-RMW epilogue +
// 8-MFMA density): Wo -> 4-wave BN=128 ring-3 writing a PURE f32 partial
// (no x read); residual+bias folded into ln2 (x += woP + bo, then LN).
// embed -> BN=128. Everything else = R9.
// Workspace (155,910,144 B):
//   x    f32  @ 0
//   attn bf16 @ 25559040   } aliases P1 (disjoint lifetimes)
//   P1   f32  @ 25559040 (ends 51118080)
//   qkv  bf16 3x[8320][768] @ 38338560
//   h    bf16 @ 76677120
//   mid  @ 89456640: patches(embed) / woP f32 25.6MB (Wo->ln2) / MLP1 out bf16
//   wbuf bf16 @ 140574720   lwt bf16 @ 154730496
// ============================================================================

typedef __bf16 bf16x8 __attribute__((ext_vector_type(8)));
typedef float  f32x4  __attribute__((ext_vector_type(4)));

#define DEVINL __device__ __forceinline__

DEVINL uint16_t f2bf(float f){
  union U{float f; uint32_t i;} v; v.f=f; uint32_t u=v.i;
  return (uint16_t)((u + 0x7fffu + ((u>>16)&1u)) >> 16);   // RNE
}

DEVINL void gl_lds16(const void* g, void* l){
  __builtin_amdgcn_global_load_lds((const __attribute__((address_space(1))) void*)g,
                                   (__attribute__((address_space(3))) void*)l, 16, 0, 0);
}

// ---------------- patchify
__global__ __launch_bounds__(256) void patchify_k(const float* __restrict__ img,
                                                  uint16_t* __restrict__ out){
  int i = blockIdx.x*256 + threadIdx.x;
  int m  = i / 768, kk = i - m*768;
  int b  = m >> 6,  t  = m & 63;
  int py = t >> 3,  px = t & 7;
  int r  = kk / 48, rem = kk - r*48;
  size_t src = ((size_t)(b*128 + py*16 + r)*128 + px*16)*3 + rem;
  out[i] = f2bf(img[src]);
}

// ---------------- 32x32 transpose + f32->bf16
DEVINL void tile_transpose(const float* __restrict__ src, uint16_t* __restrict__ dst,
                           int R, int C, int ti, int tj, int tid){
  __shared__ uint16_t tile[32][33];
  int tx = tid & 31, ty = tid >> 5;
  int r0 = ti*32, c0 = tj*32;
  #pragma unroll
  for (int i=0;i<4;++i)
    tile[ty+i*8][tx] = f2bf(src[(size_t)(r0+ty+i*8)*C + c0 + tx]);
  __syncthreads();
  #pragma unroll
  for (int i=0;i<4;++i)
    dst[(size_t)(c0+ty+i*8)*R + r0 + tx] = tile[tx][ty+i*8];
}

__global__ __launch_bounds__(256) void transpose_cvt_k(const float* __restrict__ src,
                                                       uint16_t* __restrict__ dst, int R, int C){
  tile_transpose(src, dst, R, C, blockIdx.y, blockIdx.x, threadIdx.x);
}

__global__ __launch_bounds__(256) void prep_layer_k(
    const float* __restrict__ Wq, const float* __restrict__ Wk,
    const float* __restrict__ Wv, const float* __restrict__ Wo,
    const float* __restrict__ W1, const float* __restrict__ W2,
    uint16_t* __restrict__ wbuf){
  int idx = blockIdx.x;
  const float* src; uint16_t* dst; int R, C, ti, tj;
  if (idx < 2304){
    int m = idx / 576, t = idx - m*576; ti = t/24; tj = t - ti*24; R=768; C=768;
    src = (m==0)?Wq:(m==1)?Wk:(m==2)?Wv:Wo;
    dst = wbuf + (size_t)m*589824;
  } else if (idx < 4608){
    int t = idx - 2304; ti = t/96; tj = t - ti*96; R=768; C=3072;
    src = W1; dst = wbuf + 2359296;
  } else {
    int t = idx - 4608; ti = t/24; tj = t - ti*24; R=3072; C=768;
    src = W2; dst = wbuf + 4718592;
  }
  tile_transpose(src, dst, R, C, ti, tj, threadIdx.x);
}

__global__ __launch_bounds__(256) void cls_init_k(const float* __restrict__ ct,
                                                  const float* __restrict__ pos,
                                                  float* __restrict__ X){
  int b = blockIdx.x, tid = threadIdx.x;
  for (int e = tid; e < 768; e += 256)
    X[(size_t)b*65*768 + e] = ct[e] + pos[e];
}

// ---------------- LayerNorm.
// MODE0: v = x            (plain)
// MODE1: v = x + P1       (fold MLP2 split-K partial), write x back
// MODE2: v = x + P1 + b2  (fold Wo f32 partial + bias bo), write x back
template<int MODE>
__global__ __launch_bounds__(256) void ln_k(const float* __restrict__ Xin,
                                            float* __restrict__ Xout,
                                            const float* __restrict__ P1,
                                            const float* __restrict__ bias2,
                                            uint16_t* __restrict__ H,
                                            const float* __restrict__ g,
                                            const float* __restrict__ b){
  int row = blockIdx.x, tid = threadIdx.x;
  const size_t ro = (size_t)row*768;
  const float* xr = Xin + ro;
  float v0, v1, v2;
  if constexpr (MODE==1){
    const float* p1 = P1 + ro;
    v0 = xr[tid]     + p1[tid];
    v1 = xr[tid+256] + p1[tid+256];
    v2 = xr[tid+512] + p1[tid+512];
    float* xo = Xout + ro;
    xo[tid] = v0; xo[tid+256] = v1; xo[tid+512] = v2;
  } else if constexpr (MODE==2){
    const float* p1 = P1 + ro;
    v0 = xr[tid]     + p1[tid]     + bias2[tid];
    v1 = xr[tid+256] + p1[tid+256] + bias2[tid+256];
    v2 = xr[tid+512] + p1[tid+512] + bias2[tid+512];
    float* xo = Xout + ro;
    xo[tid] = v0; xo[tid+256] = v1; xo[tid+512] = v2;
  } else {
    v0 = xr[tid]; v1 = xr[tid+256]; v2 = xr[tid+512];
  }
  int wid = tid>>6, lane = tid&63;
  __shared__ float part[4];
  __shared__ float bc[2];
  float s = v0+v1+v2;
  #pragma unroll
  for (int o=32;o;o>>=1) s += __shfl_down(s,o);
  if (lane==0) part[wid] = s;
  __syncthreads();
  if (tid==0) bc[0] = (part[0]+part[1]+part[2]+part[3]) * (1.f/768.f);
  __syncthreads();
  float mu = bc[0];
  float d0=v0-mu, d1=v1-mu, d2=v2-mu;
  float q = d0*d0 + d1*d1 + d2*d2;
  #pragma unroll
  for (int o=32;o;o>>=1) q += __shfl_down(q,o);
  __syncthreads();
  if (lane==0) part[wid] = q;
  __syncthreads();
  if (tid==0) bc[1] = rsqrtf((part[0]+part[1]+part[2]+part[3])*(1.f/768.f) + 1e-5f);
  __syncthreads();
  float rs = bc[1];
  uint16_t* hr = H + ro;
  hr[tid]     = f2bf(d0*rs*g[tid]     + b[tid]);
  hr[tid+256] = f2bf(d1*rs*g[tid+256] + b[tid+256]);
  hr[tid+512] = f2bf(d2*rs*g[tid+512] + b[tid+512]);
}

enum { EP_BF16=0, EP_RES=1, EP_RELU=2, EP_EMB=3, EP_OUTF32=4 };

// ---------------- 4-wave GEMM (BM=128, BN=128) — embed (EP_EMB) + Wo (EP_OUTF32)
template<int MODE, int BN>
__global__ __launch_bounds__(256) void gemm_bt_k(
    const uint16_t* __restrict__ A, const uint16_t* __restrict__ Bt,
    int M, int N, int K, int strideB, long long strideO,
    const float* __restrict__ bias, float* __restrict__ X,
    uint16_t* __restrict__ Obf, const float* __restrict__ pos,
    float* __restrict__ Pout)
{
  constexpr int WN = BN/2;
  constexpr int NF = WN/16;
  constexpr int BLOADS = BN/64;
  __shared__ __align__(16) uint16_t sA[3][128*32];
  __shared__ __align__(16) uint16_t sB[3][BN*32];
  const int tid = threadIdx.x;
  const int wid = tid>>6, lane = tid&63;
  const int nx = gridDim.x;
  const int nwg = nx*gridDim.y;
  int idx = blockIdx.y*nx + blockIdx.x;
  int q8 = nwg>>3, r8 = nwg&7, xcd = idx&7, off = idx>>3;
  int swz = (xcd<r8 ? xcd*(q8+1) : r8*(q8+1) + (xcd-r8)*q8) + off;
  const int bn = (swz % nx)*BN, bm = (swz / nx)*128;
  const int z = blockIdx.z;
  const uint16_t* Bz = Bt + (size_t)z*strideB;
  const int wr = wid>>1, wc = wid&1;
  const int frow = lane&15, g = lane>>4;
  int srA[2], scA[2];
  #pragma unroll
  for (int rr=0; rr<2; ++rr){
    int G = rr*256 + tid;
    srA[rr] = G>>2; scA[rr] = ((G&3) - (G>>3)) & 3;
  }
  int srB[BLOADS], scB[BLOADS];
  #pragma unroll
  for (int rr=0; rr<BLOADS; ++rr){
    int G = rr*256 + tid;
    srB[rr] = G>>2; scB[rr] = ((G&3) - (G>>3)) & 3;
  }
  const int rsw = (frow>>1)&3;
  f32x4 acc[4][NF] = {};
  const int nt = K>>5;

  auto stage = [&](char* dA, char* dB, int k0){
    #pragma unroll
    for (int rr=0; rr<2; ++rr)
      gl_lds16(A + (size_t)(bm+srA[rr])*K + k0 + scA[rr]*8, dA + (rr*256 + wid*64)*16);
    #pragma unroll
    for (int rr=0; rr<BLOADS; ++rr)
      gl_lds16(Bz + (size_t)(bn+srB[rr])*K + k0 + scB[rr]*8, dB + (rr*256 + wid*64)*16);
  };

  char *cA=(char*)sA[0], *nA=(char*)sA[1], *fA=(char*)sA[2];
  char *cB=(char*)sB[0], *nB=(char*)sB[1], *fB=(char*)sB[2];
  stage(cA, cB, 0);
  stage(nA, nB, 32);

  for (int t = 0; t < nt; ++t){
    if (t+2 < nt){
      stage(fA, fB, (t+2)<<5);
      if constexpr (BLOADS==1) asm volatile("s_waitcnt vmcnt(6)" ::: "memory");
      else                     asm volatile("s_waitcnt vmcnt(8)" ::: "memory");
    } else if (t+1 < nt){
      if constexpr (BLOADS==1) asm volatile("s_waitcnt vmcnt(3)" ::: "memory");
      else                     asm volatile("s_waitcnt vmcnt(4)" ::: "memory");
    } else {
      asm volatile("s_waitcnt vmcnt(0)" ::: "memory");
    }
    __builtin_amdgcn_s_barrier();
    bf16x8 a[4], b[NF];
    #pragma unroll
    for (int m=0;m<4;++m)
      a[m] = *(const bf16x8*)(cA + (wr*64+m*16+frow)*64 + (((g+rsw)&3)<<4));
    #pragma unroll
    for (int n=0;n<NF;++n)
      b[n] = *(const bf16x8*)(cB + (wc*WN+n*16+frow)*64 + (((g+rsw)&3)<<4));
    #pragma unroll
    for (int m=0;m<4;++m)
      #pragma unroll
      for (int n=0;n<NF;++n)
        acc[m][n] = __builtin_amdgcn_mfma_f32_16x16x32_bf16(a[m], b[n], acc[m][n], 0,0,0);
    __builtin_amdgcn_s_barrier();
    char* t1=cA; cA=nA; nA=fA; fA=t1;
    char* t2=cB; cB=nB; nB=fB; fB=t2;
  }

  uint16_t* Oz = Obf ? Obf + (size_t)z*(size_t)strideO : nullptr;
  #pragma unroll
  for (int m=0;m<4;++m){
    int gr0 = bm + wr*64 + m*16 + (lane>>4)*4;
    #pragma unroll
    for (int n=0;n<NF;++n){
      int gc = bn + wc*WN + n*16 + (lane&15);
      #pragma unroll
      for (int r=0;r<4;++r){
        int grow = gr0 + r;
        float vsum = acc[m][n][r];
        if constexpr (MODE==EP_BF16){
          Oz[(size_t)grow*N + gc] = f2bf(vsum);
        } else if constexpr (MODE==EP_RES){
          X[(size_t)grow*N + gc] += vsum + bias[gc];
        } else if constexpr (MODE==EP_RELU){
          float u = vsum + bias[gc];
          Oz[(size_t)grow*N + gc] = f2bf(u > 0.f ? u : 0.f);
        } else if constexpr (MODE==EP_OUTF32){
          Pout[(size_t)grow*N + gc] = vsum;        // pure write, no RMW
        } else {                                   // EP_EMB
          int t2i = grow & 63, bb = grow >> 6;
          X[((size_t)bb*65 + 1 + t2i)*768 + gc] = vsum + pos[(size_t)(t2i+1)*768 + gc];
        }
      }
    }
  }
}

// ---------------- 8-wave dual-M GEMM (BM=256, BN=128): QKV / MLP1 / MLP2
// SK==2 (EP_RES): z0 X+=bias RMW, z1 writes fp32 partial P1.
template<int MODE, int SK>
__global__ __launch_bounds__(512) void gemm2m_k(
    const uint16_t* __restrict__ A, const uint16_t* __restrict__ Bt,
    int M, int N, int K, int strideB, long long strideO,
    const float* __restrict__ bias, float* __restrict__ X,
    uint16_t* __restrict__ Obf, float* __restrict__ P1)
{
  __shared__ __align__(16) uint16_t sA[2][256*32];
  __shared__ __align__(16) uint16_t sB[2][128*32];
  const int tid = threadIdx.x;
  const int wid = tid>>6, lane = tid&63;
  const int nx = gridDim.x;
  const int nwg = nx*gridDim.y;
  int idx = blockIdx.y*nx + blockIdx.x;
  int q8 = nwg>>3, r8 = nwg&7, xcd = idx&7, off = idx>>3;
  int swz = (xcd<r8 ? xcd*(q8+1) : r8*(q8+1) + (xcd-r8)*q8) + off;
  const int bn = (swz % nx)*128, bm = (swz / nx)*256;
  const int z = blockIdx.z;
  const uint16_t* Bz = (SK==1) ? Bt + (size_t)z*strideB : Bt;
  const int kbase = (SK==1) ? 0 : z*(K/SK);
  const int KS = (SK==1) ? K : K/SK;
  const int wr = wid>>1, wc = wid&1;               // 4M x 2N
  const int frow = lane&15, g = lane>>4;
  int srA[2], scA[2];
  #pragma unroll
  for (int rr=0; rr<2; ++rr){
    int G = rr*512 + tid;
    srA[rr] = G>>2; scA[rr] = ((G&3) - (G>>3)) & 3;
  }
  const int srB = tid>>2, scB = ((tid&3) - (tid>>3)) & 3;
  const int rsw = (frow>>1)&3;
  f32x4 acc[4][4] = {};
  const int nt = KS>>5;

  auto stage = [&](int bsel, int k0){
    char* dA = (char*)sA[bsel]; char* dB = (char*)sB[bsel];
    #pragma unroll
    for (int rr=0; rr<2; ++rr)
      gl_lds16(A + (size_t)(bm+srA[rr])*K + kbase + k0 + scA[rr]*8,
               dA + (rr*512 + wid*64)*16);
    gl_lds16(Bz + (size_t)(bn+srB)*K + kbase + k0 + scB*8, dB + (wid*64)*16);
  };

  stage(0, 0);
  int buf = 0;
  for (int t = 0; t < nt; ++t){
    if (t+1 < nt){
      stage(buf^1, (t+1)<<5);
      asm volatile("s_waitcnt vmcnt(3)" ::: "memory");
    } else {
      asm volatile("s_waitcnt vmcnt(0)" ::: "memory");
    }
    __builtin_amdgcn_s_barrier();
    const char* sAc = (const char*)sA[buf];
    const char* sBc = (const char*)sB[buf];
    bf16x8 a[4], b[4];
    #pragma unroll
    for (int m=0;m<4;++m)
      a[m] = *(const bf16x8*)(sAc + (wr*64+m*16+frow)*64 + (((g+rsw)&3)<<4));
    #pragma unroll
    for (int n=0;n<4;++n)
      b[n] = *(const bf16x8*)(sBc + (wc*64+n*16+frow)*64 + (((g+rsw)&3)<<4));
    #pragma unroll
    for (int m=0;m<4;++m)
      #pragma unroll
      for (int n=0;n<4;++n)
        acc[m][n] = __builtin_amdgcn_mfma_f32_16x16x32_bf16(a[m], b[n], acc[m][n], 0,0,0);
    __builtin_amdgcn_s_barrier();
    buf ^= 1;
  }

  uint16_t* Oz = Obf ? Obf + (size_t)z*(size_t)strideO : nullptr;
  #pragma unroll
  for (int m=0;m<4;++m){
    int gr0 = bm + wr*64 + m*16 + (lane>>4)*4;
    #pragma unroll
    for (int n=0;n<4;++n){
      int gc = bn + wc*64 + n*16 + (lane&15);
      #pragma unroll
      for (int r=0;r<4;++r){
        int grow = gr0 + r;
        if (grow < M){
          float vsum = acc[m][n][r];
          if constexpr (MODE==EP_BF16){
            Oz[(size_t)grow*N + gc] = f2bf(vsum);
          } else if constexpr (MODE==EP_RES){
            if constexpr (SK==1){
              X[(size_t)grow*N + gc] += vsum + bias[gc];
            } else {
              if (z==0) X[(size_t)grow*N + gc] += vsum + bias[gc];
              else      P1[(size_t)grow*N + gc] = vsum;
            }
          } else if constexpr (MODE==EP_RELU){
            float u = vsum + bias[gc];
            Oz[(size_t)grow*N + gc] = f2bf(u > 0.f ? u : 0.f);
          }
        }
      }
    }
  }
}

// ---------------- MFMA attention: one block (5 waves) per (b,head)
__global__ __launch_bounds__(320) void attn_mfma_k(const uint16_t* __restrict__ q,
    const uint16_t* __restrict__ k, const uint16_t* __restrict__ v,
    uint16_t* __restrict__ o)
{
  __shared__ __align__(16) uint16_t P_lds[80][104];
  __shared__ __align__(16) uint16_t Vt[64][104];
  const int bh = blockIdx.x; const int b = bh / 12, hd = bh - b*12;
  const int tid = threadIdx.x;
  const int m = tid>>6;
  const int lane = tid&63;
  const int g = lane>>4, c = lane&15;
  const size_t base = (size_t)b*65*768 + (size_t)hd*64;

  for (int i = tid; i < 80*16; i += 320) P_lds[i>>4][80 + (i&15)] = 0;
  for (int i = tid; i < 64*32; i += 320) Vt[i>>5][64 + (i&31)] = 0;
  __syncthreads();
  for (int j = tid; j < 520; j += 320){
    int key = j >> 3, dc = j & 7;
    union { bf16x8 v8; uint16_t u[8]; } gv;
    gv.v8 = *(const bf16x8*)&v[base + (size_t)key*768 + dc*8];
    #pragma unroll
    for (int e = 0; e < 8; ++e) Vt[dc*8 + e][key] = gv.u[e];
  }

  bf16x8 bk[5][2];
  #pragma unroll
  for (int n=0;n<5;++n)
    #pragma unroll
    for (int kk=0;kk<2;++kk)
      bk[n][kk] = *(const bf16x8*)&k[base + (size_t)(n*16 + c)*768 + kk*32 + g*8];

  bf16x8 aq[2];
  #pragma unroll
  for (int kk=0;kk<2;++kk)
    aq[kk] = *(const bf16x8*)&q[base + (size_t)(m*16 + c)*768 + kk*32 + g*8];
  f32x4 sacc[5] = {};
  #pragma unroll
  for (int kk=0;kk<2;++kk)
    #pragma unroll
    for (int n=0;n<5;++n)
      sacc[n] = __builtin_amdgcn_mfma_f32_16x16x32_bf16(aq[kk], bk[n][kk], sacc[n], 0,0,0);

  const float scale = 0.03608439182435161f;
  #pragma unroll
  for (int r=0;r<4;++r){
    float val[5]; float mx = -3.0e38f;
    #pragma unroll
    for (int n=0;n<5;++n){
      val[n] = (n*16 + c) < 65 ? sacc[n][r]*scale : -3.0e38f;
      mx = fmaxf(mx, val[n]);
    }
    #pragma unroll
    for (int off=1; off<16; off<<=1) mx = fmaxf(mx, __shfl_xor(mx, off));
    float p[5], sum = 0.f;
    #pragma unroll
    for (int n=0;n<5;++n){
      p[n] = (n*16 + c) < 65 ? __expf(val[n]-mx) : 0.f;
      sum += p[n];
    }
    #pragma unroll
    for (int off=1; off<16; off<<=1) sum += __shfl_xor(sum, off);
    float rinv = 1.f / sum;
    int row = m*16 + g*4 + r;
    #pragma unroll
    for (int n=0;n<5;++n) P_lds[row][n*16 + c] = f2bf(p[n]*rinv);
  }
  __syncthreads();

  bf16x8 vb[4][3];
  #pragma unroll
  for (int n=0;n<4;++n)
    #pragma unroll
    for (int kk=0;kk<3;++kk)
      vb[n][kk] = *(const bf16x8*)&Vt[n*16 + c][kk*32 + g*8];
  f32x4 oacc[4] = {};
  #pragma unroll
  for (int kk=0;kk<3;++kk){
    bf16x8 pa = *(const bf16x8*)&P_lds[m*16 + c][kk*32 + g*8];
    #pragma unroll
    for (int n=0;n<4;++n)
      oacc[n] = __builtin_amdgcn_mfma_f32_16x16x32_bf16(pa, vb[n][kk], oacc[n], 0,0,0);
  }
  #pragma unroll
  for (int r=0;r<4;++r){
    int row = m*16 + g*4 + r;
    if (row < 65){
      #pragma unroll
      for (int n=0;n<4;++n)
        o[base + (size_t)row*768 + n*16 + c] = f2bf(oacc[n][r]);
    }
  }
}

// ---------------- head: logits = softmax((x+P1)[cls] @ head_w + b)
__global__ __launch_bounds__(256) void head_k(const float* __restrict__ X,
    const float* __restrict__ P1,
    const float* __restrict__ W, const float* __restrict__ bias,
    float* __restrict__ out){
  int b = blockIdx.x, a = threadIdx.x;
  const size_t ro = (size_t)b*65*768;
  const float* xr = X + ro;
  const float* p1 = P1 + ro;
  float acc = bias[a];
  for (int kk=0; kk<768; ++kk)
    acc += (xr[kk]+p1[kk])*W[(size_t)kk*256 + a];
  int wid = a>>6, lane = a&63;
  __shared__ float red[4];
  float mx = acc;
  #pragma unroll
  for (int off=32; off; off>>=1) mx = fmaxf(mx, __shfl_xor(mx, off));
  if (lane==0) red[wid]=mx;
  __syncthreads();
  mx = fmaxf(fmaxf(red[0],red[1]), fmaxf(red[2],red[3]));
  float e = __expf(acc-mx);
  float s = e;
  #pragma unroll
  for (int off=32; off; off>>=1) s += __shfl_xor(s, off);
  __syncthreads();
  if (lane==0) red[wid]=s;
  __syncthreads();
  s = red[0]+red[1]+red[2]+red[3];
  out[(size_t)b*256 + a] = e/s;
}

// ============================================================================
extern "C" void kernel_launch(void* const* d_in, const int* in_sizes, int n_in,
                              void* d_out, int out_size, void* d_ws, size_t ws_size,
                              hipStream_t stream)
{
  const float* images = (const float*)d_in[0];
  const float* lin_w  = (const float*)d_in[1];
  const float* cls_tok= (const float*)d_in[2];
  const float* pos    = (const float*)d_in[3];
  const float* Wq = (const float*)d_in[4];
  const float* Wk = (const float*)d_in[5];
  const float* Wv = (const float*)d_in[6];
  const float* Wo = (const float*)d_in[7];
  const float* bo = (const float*)d_in[8];
  const float* ln1g=(const float*)d_in[9];
  const float* ln1b=(const float*)d_in[10];
  const float* ln2g=(const float*)d_in[11];
  const float* ln2b=(const float*)d_in[12];
  const float* W1 = (const float*)d_in[13];
  const float* b1 = (const float*)d_in[14];
  const float* W2 = (const float*)d_in[15];
  const float* b2 = (const float*)d_in[16];
  const float* hw = (const float*)d_in[17];
  const float* hb = (const float*)d_in[18];

  char* ws = (char*)d_ws;
  float*    x    = (float*)   (ws + 0);
  uint16_t* attn = (uint16_t*)(ws + 25559040);     // aliases P1 (disjoint phases)
  float*    P1   = (float*)   (ws + 25559040);
  uint16_t* qkv  = (uint16_t*)(ws + 38338560);     // 3 slices of [8320][768]
  uint16_t* h    = (uint16_t*)(ws + 76677120);
  uint16_t* mid  = (uint16_t*)(ws + 89456640);     // patches / woP / MLP1 out
  float*    woP  = (float*)   (ws + 89456640);     // f32 25.6MB, Wo -> ln2
  uint16_t* wbuf = (uint16_t*)(ws + 140574720);
  uint16_t* lwt  = (uint16_t*)(ws + 154730496);

  // embed
  patchify_k<<<24576,256,0,stream>>>(images, mid);
  transpose_cvt_k<<<dim3(24,24),256,0,stream>>>(lin_w, lwt, 768, 768);
  gemm_bt_k<EP_EMB,128><<<dim3(6,64,1),256,0,stream>>>(mid, lwt, 8192,768,768, 0,0,
                                                   nullptr, x, nullptr, pos, nullptr);
  cls_init_k<<<128,256,0,stream>>>(cls_tok, pos, x);

  for (int l=0;l<12;++l){
    prep_layer_k<<<6912,256,0,stream>>>(Wq+(size_t)l*589824, Wk+(size_t)l*589824,
                                        Wv+(size_t)l*589824, Wo+(size_t)l*589824,
                                        W1+(size_t)l*2359296, W2+(size_t)l*2359296, wbuf);
    if (l==0)
      ln_k<0><<<8320,256,0,stream>>>(x, nullptr, nullptr, nullptr, h, ln1g, ln1b);
    else
      ln_k<1><<<8320,256,0,stream>>>(x, x, P1, nullptr, h,
                                     ln1g+(size_t)l*768, ln1b+(size_t)l*768);
    gemm2m_k<EP_BF16,1><<<dim3(6,33,3),512,0,stream>>>(h, wbuf, 8320,768,768,
                                                       589824, 6389760LL,
                                                       nullptr, nullptr, qkv, nullptr);
    attn_mfma_k<<<1536,320,0,stream>>>(qkv, qkv+6389760, qkv+12779520, attn);
    // Wo: pure f32 partial (no x RMW); residual+bias folded into ln2
    gemm_bt_k<EP_OUTF32,128><<<dim3(6,65,1),256,0,stream>>>(attn, wbuf+1769472,
                                                     8320,768,768, 0,0,
                                                     nullptr, nullptr, nullptr, nullptr, woP);
    ln_k<2><<<8320,256,0,stream>>>(x, x, woP, bo+(size_t)l*768, h,
                                   ln2g+(size_t)l*768, ln2b+(size_t)l*768);
    gemm2m_k<EP_RELU,1><<<dim3(24,33,1),512,0,stream>>>(h, wbuf+2359296, 8320,3072,768,
                                                        0,0, b1+(size_t)l*3072, nullptr, mid, nullptr);
    gemm2m_k<EP_RES,2><<<dim3(6,33,2),512,0,stream>>>(mid, wbuf+4718592, 8320,768,3072,
                                                      0,0, b2+(size_t)l*768, x, nullptr, P1);
  }
  head_k<<<128,256,0,stream>>>(x, P1, hw, hb, (float*)d_out);
}